// Round 13
// baseline (180.887 us; speedup 1.0000x reference)
//
#include <hip/hip_runtime.h>
#include <hip/hip_bf16.h>
#include <hip/hip_fp8.h>

// ContrastiveLoss fused kernel for MI355X (gfx950).
//
// Math reduction (T=0.5):
//   f = x / max(||x||, 1e-8)   (rows)
//   s_ij = f_i . f_j
//   den_i = sum_{j: label_j != label_i} exp(2 s_ij)
//   loss  = sum_i [ c_i * log(den_i) - sum_{j same label, j != i} 2 s_ij ]
//           / (sum_i c_i + 1e-5),   c_i = count(label_i) - 1
//
// N=4096, D=512, labels in [0,100).
//
// Round 13: single plain kernel + HAND-ROLLED GRID BARRIER (R12's
// hipLaunchCooperativeKernel silently no-ops under graph capture:
// absmax == |ref| -> out never written). Co-residency is guaranteed by
// capacity arithmetic: GRID=512 = 2 blocks/CU, 256 thr, ~18 KB LDS,
// ~110 VGPR (<=256/wave at 8 waves/CU). Barrier: atomic cnt + gen flag,
// __threadfence release/acquire (emits cross-XCD L2 wb/inv on gfx950);
// state zeroed per call by hipMemsetAsync (graph-capturable).
// Retile to TI=64: 2080 symmetric pairs grid-strided over 512 blocks
// (4.06/block, ~23% tail imbalance vs 2x at TI=128). A = 1 fragment
// group/wave (32 VGPR). fp8 e4m3 16x16x32 MFMA, kt-paired LDS chunks,
// fragment-major global layout (all proven R11).

typedef float floatx4 __attribute__((ext_vector_type(4)));
typedef long lng2 __attribute__((ext_vector_type(2)));
typedef unsigned int u32;
typedef unsigned char u8;

#define N_ROWS 4096
#define DIM 512
#define GRPB 8192              // bytes per 16-row fp8 fragment group (16*512)
#define EPS_NORM 1e-8f
#define EPS_DEN 1e-5f
#define TI 64                  // tile size (rows and cols)
#define NT (N_ROWS / TI)       // 64 tiles
#define NPAIR (NT * (NT + 1) / 2)   // 2080 pairs
#define NSLAB (TI / 16)        // 4 slabs of 16 j-rows per tile
#define GRID 512

static __device__ inline void load_lds16(const char* g, char* l) {
  __builtin_amdgcn_global_load_lds(
      (const __attribute__((address_space(1))) void*)g,
      (__attribute__((address_space(3))) void*)l, 16, 0, 0);
}

static __device__ inline void grid_barrier(int* cnt, int* gen) {
  __syncthreads();
  if (threadIdx.x == 0) {
    __threadfence();   // release: publish this block's writes device-wide
    int g = __hip_atomic_load(gen, __ATOMIC_RELAXED, __HIP_MEMORY_SCOPE_AGENT);
    int old = atomicAdd(cnt, 1);
    if (old == GRID - 1) {
      __hip_atomic_store(cnt, 0, __ATOMIC_RELAXED, __HIP_MEMORY_SCOPE_AGENT);
      __hip_atomic_store(gen, g + 1, __ATOMIC_RELEASE, __HIP_MEMORY_SCOPE_AGENT);
    } else {
      while (__hip_atomic_load(gen, __ATOMIC_ACQUIRE,
                               __HIP_MEMORY_SCOPE_AGENT) == g)
        __builtin_amdgcn_s_sleep(8);
    }
    __threadfence();   // acquire: invalidate stale cached lines
  }
  __syncthreads();
}

__global__ __launch_bounds__(256, 2) void mega(
    const float* __restrict__ x, const int* __restrict__ labels,
    u8* __restrict__ G, u8* __restrict__ lab8,
    float* __restrict__ den, float* __restrict__ pos,
    float* acc2, int* bar, float* __restrict__ out) {
  // fp8 B slab: 2 buffers x 8 KB (16 rows x 512 k, kt-paired 1 KB chunks)
  __shared__ u8 Bsh[2 * 8192];
  __shared__ int labj_sh[TI];
  __shared__ float colden[TI], colpos[TI];
  __shared__ int hist[128];
  __shared__ float sred[8];

  const char* Gb = (const char*)G;
  char* bshb = (char*)Bsh;

  const int bid = blockIdx.x;
  const int tid = threadIdx.x;
  const int wv = tid >> 6;
  const int lane = tid & 63;
  const int l15 = lane & 15;
  const int kg4 = lane >> 4;              // 0..3 (16-col groups)

  int* cnt = bar;        // zeroed by hipMemsetAsync each call
  int* gen = bar + 1;
  int* done = bar + 2;

  // ================= phase 1: normalize + fp8 pack =================
  // G layout (fp8): group g = row>>4 (8192 B), kt-pair p = kt>>1 (1024 B);
  // consumer lane l = kq*16 + (row&15) holds fragment of kt at byte
  // l*16 + (kt&1)*8, covering k = kt*32 + kq*8 .. +8.
#pragma unroll
  for (int rr = 0; rr < 2; ++rr) {
    const int row = bid * 8 + wv * 2 + rr;
    const float4* src = reinterpret_cast<const float4*>(x + (size_t)row * DIM);
    float4 v0 = src[lane * 2];
    float4 v1 = src[lane * 2 + 1];
    float ss = v0.x*v0.x + v0.y*v0.y + v0.z*v0.z + v0.w*v0.w
             + v1.x*v1.x + v1.y*v1.y + v1.z*v1.z + v1.w*v1.w;
#pragma unroll
    for (int m = 1; m < 64; m <<= 1) ss += __shfl_xor(ss, m, 64);
    float scale = 1.f / fmaxf(sqrtf(ss), EPS_NORM);

    u32 lo = ((u32)__hip_fp8_e4m3(v0.x * scale).__x)
           | ((u32)__hip_fp8_e4m3(v0.y * scale).__x << 8)
           | ((u32)__hip_fp8_e4m3(v0.z * scale).__x << 16)
           | ((u32)__hip_fp8_e4m3(v0.w * scale).__x << 24);
    u32 hi = ((u32)__hip_fp8_e4m3(v1.x * scale).__x)
           | ((u32)__hip_fp8_e4m3(v1.y * scale).__x << 8)
           | ((u32)__hip_fp8_e4m3(v1.z * scale).__x << 16)
           | ((u32)__hip_fp8_e4m3(v1.w * scale).__x << 24);
    uint2 o; o.x = lo; o.y = hi;

    const int kt = lane >> 2;
    const int kq = lane & 3;
    char* dst = (char*)G + (size_t)(row >> 4) * GRPB + (kt >> 1) * 1024
              + (kq * 16 + (row & 15)) * 16 + (kt & 1) * 8;
    *reinterpret_cast<uint2*>(dst) = o;

    if (lane == 0) { den[row] = 0.f; pos[row] = 0.f; }
    if (lane == 1) lab8[row] = (u8)labels[row];
  }
  if (bid == 0 && tid == 0) { acc2[0] = 0.f; acc2[1] = 0.f; }

  grid_barrier(cnt, gen);

  // ============ phase 2: fp8 sim-GEMM over symmetric tile pairs ============
  for (int u = bid; u < NPAIR; u += GRID) {
    // decode pair (ti, tj), ti <= tj
    int b = u;
    int ti = 0, rem = NT;
    while (b >= rem) { b -= rem; ++ti; --rem; }
    const int tj = ti + b;
    const bool diag = (ti == tj);

    const int ib = ti * TI;
    const int jb = tj * TI;

    // stage one 16-row fp8 slab (8 KB = 8 chunks); wave wv stages chunks
    // wv*2, wv*2+1. Source AND dest contiguous 1 KB (lane*16).
#define STAGE(bufsel, slab) do {                                            \
    _Pragma("unroll")                                                       \
    for (int i_ = 0; i_ < 2; ++i_) {                                        \
      const int c_ = wv * 2 + i_;                                           \
      load_lds16(Gb + (size_t)(tj * NSLAB + (slab)) * GRPB + c_ * 1024 + lane * 16, \
                 bshb + (bufsel) * 8192 + c_ * 1024 + lane * 16);           \
    }                                                                       \
  } while (0)

    STAGE(0, 0);
    if (tid < TI) {
      labj_sh[tid] = lab8[jb + tid];
      colden[tid] = 0.f;
      colpos[tid] = 0.f;
    }

    // A fragments: 16 rows/wave = 1 fp8 fragment group -> 32 VGPRs.
    long a[16];
    {
      const char* ab = Gb + (size_t)(ti * NSLAB + wv) * GRPB + lane * 16;
#pragma unroll
      for (int q = 0; q < 8; ++q) {
        lng2 v = *reinterpret_cast<const lng2*>(ab + q * 1024);
        a[2 * q] = v.x; a[2 * q + 1] = v.y;
      }
    }
#pragma unroll
    for (int kt = 0; kt < 16; ++kt)
      asm volatile("" : "+v"(a[kt]));

    // C/D layout (verified gfx950, dtype-independent): col = lane&15 (j),
    // row = kg4*4 + r (i). lane's 4 output rows: i_base + r.
    const int i_base = ib + wv * 16 + kg4 * 4;
    const u32 labp = *reinterpret_cast<const u32*>(lab8 + i_base);

    float den_acc[4] = {0.f, 0.f, 0.f, 0.f};
    float pos_acc[4] = {0.f, 0.f, 0.f, 0.f};

    __syncthreads();   // buf0 staged, labels + col accs ready

    for (int t = 0; t < NSLAB; ++t) {
      const int cur = t & 1;
      if (t + 1 < NSLAB) STAGE(cur ^ 1, t + 1);

      const int jrow = jb + t * 16 + l15;
      const int labj = labj_sh[t * 16 + l15];

      // two independent 8-deep MFMA chains (even/odd kt)
      floatx4 acc_a = {0.f,0.f,0.f,0.f};
      floatx4 acc_b = {0.f,0.f,0.f,0.f};
      const char* bbase = bshb + cur * 8192 + lane * 16;
#pragma unroll
      for (int q = 0; q < 8; ++q) {
        lng2 b2 = *reinterpret_cast<const lng2*>(bbase + q * 1024);
        acc_a = __builtin_amdgcn_mfma_f32_16x16x32_fp8_fp8(a[2*q],   b2.x, acc_a, 0, 0, 0);
        acc_b = __builtin_amdgcn_mfma_f32_16x16x32_fp8_fp8(a[2*q+1], b2.y, acc_b, 0, 0, 0);
      }

      float cd = 0.f, cp = 0.f;   // col partials for this 16-j slab
#pragma unroll
      for (int r = 0; r < 4; ++r) {
        const int labi = (int)((labp >> (8 * r)) & 255u);
        const int irow = i_base + r;
        float s2 = 2.f * (acc_a[r] + acc_b[r]);
        float e = __expf(s2);
        bool sm = (labj == labi);
        float dv = sm ? 0.f : e;
        float pv = (sm && (jrow != irow)) ? s2 : 0.f;
        den_acc[r] += dv;
        pos_acc[r] += pv;
        cd += dv; cp += pv;
      }
      if (!diag) {
        cd += __shfl_xor(cd, 16, 64); cd += __shfl_xor(cd, 32, 64);
        cp += __shfl_xor(cp, 16, 64); cp += __shfl_xor(cp, 32, 64);
        if (kg4 == 0) {
          atomicAdd(&colden[t * 16 + l15], cd);
          atomicAdd(&colpos[t * 16 + l15], cp);
        }
      }
      __syncthreads();   // staging for t+1 done; safe to flip buffers
    }

    // row path: reduce across 16 cols (lanes with same kg4), 1 atomic/row
#pragma unroll
    for (int r = 0; r < 4; ++r) {
      float dd = den_acc[r], pp = pos_acc[r];
#pragma unroll
      for (int m = 1; m < 16; m <<= 1) {
        dd += __shfl_xor(dd, m, 64);
        pp += __shfl_xor(pp, m, 64);
      }
      if (l15 == 0) {
        atomicAdd(&den[i_base + r], dd);
        atomicAdd(&pos[i_base + r], pp);
      }
    }

    // col path flush (off-diagonal): one atomic per col
    if (!diag) {
      __syncthreads();   // all waves' LDS col atomics done
      if (tid < TI) {
        atomicAdd(&den[jb + tid], colden[tid]);
        atomicAdd(&pos[jb + tid], colpos[tid]);
      }
    }
    __syncthreads();   // protect labj_sh/colden/Bsh rewrite by next unit
#undef STAGE
  }

  grid_barrier(cnt, gen);

  // ================= phase 3: finalize (blocks 0..15) =================
  if (bid < 16) {
    if (tid < 128) hist[tid] = 0;
    __syncthreads();
    for (int i = tid; i < N_ROWS; i += 256) atomicAdd(&hist[labels[i]], 1);
    __syncthreads();

    const int row = bid * 256 + tid;
    int c = hist[labels[row]] - 1;
    float dv = atomicAdd(&den[row], 0.f);   // coherent cross-XCD read
    float pv = atomicAdd(&pos[row], 0.f);
    float num = (float)c * logf(dv) - pv;
    float nnz = (float)c;
#pragma unroll
    for (int m = 1; m < 64; m <<= 1) {
      num += __shfl_xor(num, m, 64);
      nnz += __shfl_xor(nnz, m, 64);
    }
    if ((tid & 63) == 0) { sred[wv] = num; sred[4 + wv] = nnz; }
    __syncthreads();
    if (tid == 0) {
      atomicAdd(&acc2[0], sred[0] + sred[1] + sred[2] + sred[3]);
      atomicAdd(&acc2[1], sred[4] + sred[5] + sred[6] + sred[7]);
      __threadfence();
      int old = atomicAdd(done, 1);
      if (old == 15) {
        float tn = atomicAdd(&acc2[0], 0.f);
        float tz = atomicAdd(&acc2[1], 0.f);
        out[0] = tn / (tz + EPS_DEN);
      }
    }
  }
}

extern "C" void kernel_launch(void* const* d_in, const int* in_sizes, int n_in,
                              void* d_out, int out_size, void* d_ws, size_t ws_size,
                              hipStream_t stream) {
  const float* x = (const float*)d_in[0];
  const int* labels = (const int*)d_in[1];

  // ws: G fp8 (2MB) | den f32[4096] | pos f32[4096] | lab8 u8[4096]
  //   | acc2 f32[2] | bar i32[4] (cnt, gen, done, pad)
  u8* G = (u8*)d_ws;
  float* den = (float*)((char*)d_ws + (size_t)N_ROWS * DIM);
  float* pos = den + N_ROWS;
  u8* lab8 = (u8*)(pos + N_ROWS);
  float* acc2 = (float*)(lab8 + N_ROWS);
  int* bar = (int*)(acc2 + 2);
  float* out = (float*)d_out;

  hipMemsetAsync(bar, 0, 4 * sizeof(int), stream);
  hipLaunchKernelGGL(mega, dim3(GRID), dim3(256), 0, stream,
                     x, labels, G, lab8, den, pos, acc2, bar, out);
}

// Round 14
// 36.842 us; speedup vs baseline: 4.9098x; 4.9098x over previous
//
#include <hip/hip_runtime.h>
#include <hip/hip_bf16.h>
#include <hip/hip_fp8.h>

// ContrastiveLoss fused kernel for MI355X (gfx950).
//
// Math reduction (T=0.5):
//   f = x / max(||x||, 1e-8)   (rows)
//   s_ij = f_i . f_j
//   den_i = sum_{j: label_j != label_i} exp(2 s_ij)
//   loss  = sum_i [ c_i * log(den_i) - sum_{j same label, j != i} 2 s_ij ]
//           / (sum_i c_i + 1e-5),   c_i = count(label_i) - 1
//
// N=4096, D=512, labels in [0,100).
//
// Round 14: WHOLE-TILE STAGING, ZERO-BARRIER MAIN LOOP. m233 (guide):
// a 2-phase stage->drain->MFMA loop runs at ~28% of MFMA-only speed --
// the per-slab vmcnt(0)+barrier tax explains k2's stubborn ~25 us
// across R5-R11 (R9's counted-vmcnt kept per-slab barriers; R13's grid
// barrier was a 180 us disaster -- both grid-fusion variants dead).
// fp8 makes the whole 128x512 B tile 64 KB -> fits LDS at 2 blocks/CU.
// Stage it ONCE (64 x 1 KB fragment chunks, 16 global_load_lds/wave),
// ONE __syncthreads (single vmcnt drain per block), then 8 slabs x 32
// MFMA + epilogue run with NO barriers, free compiler scheduling.
// Also: k3b folded into k3a (device-atomic done counter -- correct
// without co-residency). 3 launches. Symmetric 528 tile-pairs, fp8
// e4m3 16x16x32 MFMA, fragment-major G (proven R11).

typedef float floatx4 __attribute__((ext_vector_type(4)));
typedef long lng2 __attribute__((ext_vector_type(2)));
typedef unsigned int u32;
typedef unsigned char u8;

#define N_ROWS 4096
#define DIM 512
#define GRPB 8192              // bytes per 16-row fp8 fragment group (16*512)
#define EPS_NORM 1e-8f
#define EPS_DEN 1e-5f
#define TI 128                 // tile size (rows and cols)
#define NT (N_ROWS / TI)       // 32 tiles
#define NPAIR (NT * (NT + 1) / 2)   // 528 blocks
#define NSLAB 8                // 8 slabs of 16 j-rows per tile

static __device__ inline void load_lds16(const char* g, char* l) {
  __builtin_amdgcn_global_load_lds(
      (const __attribute__((address_space(1))) void*)g,
      (__attribute__((address_space(3))) void*)l, 16, 0, 0);
}

// wave-per-row normalize + fp8 pack, fragment-major store; grid 1024 x 256.
// G layout (fp8): group g = row>>4 (8192 B), kt-pair p = kt>>1 (1024 B);
// consumer lane l = kq*16 + (row&15) holds fragment of kt at byte
// l*16 + (kt&1)*8, covering k = kt*32 + kq*8 .. +8.
__global__ void k1_normalize(const float* __restrict__ x,
                             const int* __restrict__ labels,
                             u8* __restrict__ G, u8* __restrict__ lab8,
                             float* __restrict__ den, float* __restrict__ pos,
                             float* __restrict__ acc2, int* __restrict__ done) {
  const int row = blockIdx.x * 4 + (threadIdx.x >> 6);
  const int lane = threadIdx.x & 63;
  const float4* src = reinterpret_cast<const float4*>(x + (size_t)row * DIM);
  float4 v0 = src[lane * 2];
  float4 v1 = src[lane * 2 + 1];
  float ss = v0.x*v0.x + v0.y*v0.y + v0.z*v0.z + v0.w*v0.w
           + v1.x*v1.x + v1.y*v1.y + v1.z*v1.z + v1.w*v1.w;
#pragma unroll
  for (int m = 1; m < 64; m <<= 1) ss += __shfl_xor(ss, m, 64);
  float scale = 1.f / fmaxf(sqrtf(ss), EPS_NORM);

  u32 lo = ((u32)__hip_fp8_e4m3(v0.x * scale).__x)
         | ((u32)__hip_fp8_e4m3(v0.y * scale).__x << 8)
         | ((u32)__hip_fp8_e4m3(v0.z * scale).__x << 16)
         | ((u32)__hip_fp8_e4m3(v0.w * scale).__x << 24);
  u32 hi = ((u32)__hip_fp8_e4m3(v1.x * scale).__x)
         | ((u32)__hip_fp8_e4m3(v1.y * scale).__x << 8)
         | ((u32)__hip_fp8_e4m3(v1.z * scale).__x << 16)
         | ((u32)__hip_fp8_e4m3(v1.w * scale).__x << 24);
  uint2 o; o.x = lo; o.y = hi;

  const int kt = lane >> 2;
  const int kq = lane & 3;
  char* dst = (char*)G + (size_t)(row >> 4) * GRPB + (kt >> 1) * 1024
            + (kq * 16 + (row & 15)) * 16 + (kt & 1) * 8;
  *reinterpret_cast<uint2*>(dst) = o;

  if (lane == 0) { den[row] = 0.f; pos[row] = 0.f; }
  if (lane == 1) lab8[row] = (u8)labels[row];
  if (blockIdx.x == 0 && threadIdx.x == 0) {
    acc2[0] = 0.f; acc2[1] = 0.f; done[0] = 0;
  }
}

// fused fp8 sim-GEMM + symmetric per-row/per-col reduction.
// Whole 64 KB B tile staged once; main loop barrier-free.
__global__ __launch_bounds__(256, 2) void k2_fused(
    const u8* __restrict__ G, const u8* __restrict__ lab8,
    float* __restrict__ den, float* __restrict__ pos) {
  __shared__ u8 Bsh[64 * 1024];          // whole B tile: 64 chunks x 1 KB
  __shared__ int labj_sh[TI];
  __shared__ float colden[TI], colpos[TI];

  const char* Gb = (const char*)G;
  char* bshb = (char*)Bsh;

  // decode pair (ti, tj), ti <= tj, from blockIdx
  int b = blockIdx.x;
  int ti = 0, rem = NT;
  while (b >= rem) { b -= rem; ++ti; --rem; }
  const int tj = ti + b;
  const bool diag = (ti == tj);

  const int tid = threadIdx.x;
  const int wv = tid >> 6;
  const int lane = tid & 63;
  const int l15 = lane & 15;
  const int kg4 = lane >> 4;              // 0..3 (16-col groups)

  const int ib = ti * TI;
  const int jb = tj * TI;

  // stage the WHOLE B tile (64 KB = 64 chunks); wave wv stages chunks
  // wv*16 .. wv*16+15. chunk = slab*8 + q. Contiguous 1 KB src AND dst.
#pragma unroll
  for (int c = 0; c < 16; ++c) {
    const int chunk = wv * 16 + c;
    load_lds16(Gb + (size_t)(tj * 8 + (chunk >> 3)) * GRPB
                  + (chunk & 7) * 1024 + lane * 16,
               bshb + chunk * 1024 + lane * 16);
  }
  if (tid < TI) {
    labj_sh[tid] = lab8[jb + tid];
    colden[tid] = 0.f;
    colpos[tid] = 0.f;
  }

  // A fragments: 32 rows/wave = 2 fp8 fragment groups -> 64 VGPRs.
  long a0[16], a1[16];
  {
    const char* ab0 = Gb + (size_t)(ti * 8 + wv * 2) * GRPB + lane * 16;
    const char* ab1 = ab0 + GRPB;
#pragma unroll
    for (int q = 0; q < 8; ++q) {
      lng2 v0 = *reinterpret_cast<const lng2*>(ab0 + q * 1024);
      lng2 v1 = *reinterpret_cast<const lng2*>(ab1 + q * 1024);
      a0[2 * q] = v0.x; a0[2 * q + 1] = v0.y;
      a1[2 * q] = v1.x; a1[2 * q + 1] = v1.y;
    }
  }
#pragma unroll
  for (int kt = 0; kt < 16; ++kt) {
    asm volatile("" : "+v"(a0[kt]));
    asm volatile("" : "+v"(a1[kt]));
  }

  // C/D layout (verified gfx950, dtype-independent): col = lane&15 (j),
  // row = kg4*4 + r (i). lane's 8 output rows: i_base + s*16 + r.
  const int i_base = ib + wv * 32 + kg4 * 4;
  const u32 labp0 = *reinterpret_cast<const u32*>(lab8 + i_base);
  const u32 labp1 = *reinterpret_cast<const u32*>(lab8 + i_base + 16);

  float den_acc[2][4] = {{0.f,0.f,0.f,0.f},{0.f,0.f,0.f,0.f}};
  float pos_acc[2][4] = {{0.f,0.f,0.f,0.f},{0.f,0.f,0.f,0.f}};

  __syncthreads();   // ONE drain: whole tile staged, labels + col accs ready

  // barrier-free main loop: 8 slabs x 32 MFMA + epilogue
#pragma unroll
  for (int t = 0; t < NSLAB; ++t) {
    const int jrow = jb + t * 16 + l15;
    const int labj = labj_sh[t * 16 + l15];

    floatx4 acc0 = {0.f,0.f,0.f,0.f};
    floatx4 acc1 = {0.f,0.f,0.f,0.f};
    const char* bbase = bshb + t * 8192 + lane * 16;
#pragma unroll
    for (int q = 0; q < 8; ++q) {
      lng2 b2 = *reinterpret_cast<const lng2*>(bbase + q * 1024);
      acc0 = __builtin_amdgcn_mfma_f32_16x16x32_fp8_fp8(a0[2*q],   b2.x, acc0, 0, 0, 0);
      acc1 = __builtin_amdgcn_mfma_f32_16x16x32_fp8_fp8(a1[2*q],   b2.x, acc1, 0, 0, 0);
      acc0 = __builtin_amdgcn_mfma_f32_16x16x32_fp8_fp8(a0[2*q+1], b2.y, acc0, 0, 0, 0);
      acc1 = __builtin_amdgcn_mfma_f32_16x16x32_fp8_fp8(a1[2*q+1], b2.y, acc1, 0, 0, 0);
    }

    float cd = 0.f, cp = 0.f;   // col partials for this 16-j slab
#pragma unroll
    for (int s = 0; s < 2; ++s) {
      floatx4 av = s ? acc1 : acc0;
      const u32 labp = s ? labp1 : labp0;
#pragma unroll
      for (int r = 0; r < 4; ++r) {
        const int labi = (int)((labp >> (8 * r)) & 255u);
        const int irow = i_base + s * 16 + r;
        float s2 = 2.f * av[r];
        float e = __expf(s2);
        bool sm = (labj == labi);
        float dv = sm ? 0.f : e;
        float pv = (sm && (jrow != irow)) ? s2 : 0.f;
        den_acc[s][r] += dv;
        pos_acc[s][r] += pv;
        cd += dv; cp += pv;
      }
    }
    if (!diag) {
      // reduce col partials across the 4 kg groups (lanes sharing l15)
      cd += __shfl_xor(cd, 16, 64); cd += __shfl_xor(cd, 32, 64);
      cp += __shfl_xor(cp, 16, 64); cp += __shfl_xor(cp, 32, 64);
      if (kg4 == 0) {
        atomicAdd(&colden[t * 16 + l15], cd);
        atomicAdd(&colpos[t * 16 + l15], cp);
      }
    }
  }

  // row path: reduce across 16 cols (lanes with same kg4), 1 atomic/row
#pragma unroll
  for (int s = 0; s < 2; ++s)
#pragma unroll
    for (int r = 0; r < 4; ++r) {
      float dd = den_acc[s][r], pp = pos_acc[s][r];
#pragma unroll
      for (int m = 1; m < 16; m <<= 1) {
        dd += __shfl_xor(dd, m, 64);
        pp += __shfl_xor(pp, m, 64);
      }
      if (l15 == 0) {
        atomicAdd(&den[i_base + s * 16 + r], dd);
        atomicAdd(&pos[i_base + s * 16 + r], pp);
      }
    }

  // col path flush (off-diagonal): one atomic per col
  if (!diag) {
    __syncthreads();   // all waves' LDS col atomics done
    if (tid < TI) {
      atomicAdd(&den[jb + tid], colden[tid]);
      atomicAdd(&pos[jb + tid], colpos[tid]);
    }
  }
}

// per-row finalize + scalar write: 16 blocks x 256 threads; last-done
// block (device atomics, no co-residency needed) computes the output.
__global__ void k3a(const float* __restrict__ den, const float* __restrict__ pos,
                    const int* __restrict__ labels, float* __restrict__ acc2,
                    int* __restrict__ done, float* __restrict__ out) {
  __shared__ int hist[128];
  __shared__ float sn[4], sz[4];
  const int tid = threadIdx.x;
  if (tid < 128) hist[tid] = 0;
  __syncthreads();
  for (int i = tid; i < N_ROWS; i += 256) atomicAdd(&hist[labels[i]], 1);
  __syncthreads();

  const int row = blockIdx.x * 256 + tid;
  int c = hist[labels[row]] - 1;
  float num = (float)c * logf(den[row]) - pos[row];
  float nnz = (float)c;
#pragma unroll
  for (int m = 1; m < 64; m <<= 1) {
    num += __shfl_xor(num, m, 64);
    nnz += __shfl_xor(nnz, m, 64);
  }
  if ((tid & 63) == 0) { sn[tid >> 6] = num; sz[tid >> 6] = nnz; }
  __syncthreads();
  if (tid == 0) {
    atomicAdd(&acc2[0], sn[0] + sn[1] + sn[2] + sn[3]);
    atomicAdd(&acc2[1], sz[0] + sz[1] + sz[2] + sz[3]);
    __threadfence();
    int old = atomicAdd(done, 1);
    if (old == 15) {
      float tn = atomicAdd(&acc2[0], 0.f);   // coherent device-scope read
      float tz = atomicAdd(&acc2[1], 0.f);
      out[0] = tn / (tz + EPS_DEN);
    }
  }
}

extern "C" void kernel_launch(void* const* d_in, const int* in_sizes, int n_in,
                              void* d_out, int out_size, void* d_ws, size_t ws_size,
                              hipStream_t stream) {
  const float* x = (const float*)d_in[0];
  const int* labels = (const int*)d_in[1];

  // ws: G fp8 (2MB) | den f32[4096] | pos f32[4096] | lab8 u8[4096]
  //   | acc2 f32[2] | done i32[1]
  u8* G = (u8*)d_ws;
  float* den = (float*)((char*)d_ws + (size_t)N_ROWS * DIM);
  float* pos = den + N_ROWS;
  u8* lab8 = (u8*)(pos + N_ROWS);
  float* acc2 = (float*)(lab8 + N_ROWS);
  int* done = (int*)(acc2 + 2);
  float* out = (float*)d_out;

  hipLaunchKernelGGL(k1_normalize, dim3(N_ROWS / 4), dim3(256), 0, stream,
                     x, labels, G, lab8, den, pos, acc2, done);
  hipLaunchKernelGGL(k2_fused, dim3(NPAIR), dim3(256), 0, stream,
                     G, lab8, den, pos);
  hipLaunchKernelGGL(k3a, dim3(16), dim3(256), 0, stream,
                     den, pos, labels, acc2, done, out);
}